// Round 13
// baseline (240.144 us; speedup 1.0000x reference)
//
#include <hip/hip_runtime.h>
#include <hip/hip_bf16.h>

// FraudSNN fused kernel: GEMM (bf16 MFMA) + LIF recurrence, T=10, F=256, H=512.
// R13: two goals at once under the immovable 64-VGPR budget:
//  (1) spill-free: ct-pair-split GEMM (acc 16 regs/pass, LIF right after each pass)
//  (2) 2 blocks/CU: 512 thr, 32 rows/block, LDS 75.4 KB (mem1 7 planes + m7 in regs)
//      -> two independent barrier groups per CU hide each other's pf/W1 latency.
// Keeps R12's 3-barrier/t dbuf-xt overlap, packed-uint2 pf, redundant LIF2.

typedef short short8 __attribute__((ext_vector_type(8)));
typedef float f32x4 __attribute__((ext_vector_type(4)));

__device__ __forceinline__ unsigned short bfbits(float f) {
  union { __hip_bfloat16 h; unsigned short u; } c;
  c.h = __float2bfloat16(f);   // hardware RNE
  return c.u;
}

__device__ __forceinline__ unsigned int bfpack(float a, float b) {
  return (unsigned int)bfbits(a) | ((unsigned int)bfbits(b) << 16);
}

__device__ __forceinline__ float fast_sigmoid(float z) {
  float e = __expf(-z);
  return __builtin_amdgcn_rcpf(1.0f + e);
}

__global__ void w1_to_bf16(const float* __restrict__ w1, unsigned short* __restrict__ o) {
  int i = blockIdx.x * 256 + threadIdx.x;      // 32768 float4s = 131072 floats
  float4 v = reinterpret_cast<const float4*>(w1)[i];
  reinterpret_cast<uint2*>(o)[i] = make_uint2(bfpack(v.x, v.y), bfpack(v.z, v.w));
}

__device__ __forceinline__ short8 cvt_frag(const float* p) {
  const float4 v0 = *reinterpret_cast<const float4*>(p);
  const float4 v1 = *reinterpret_cast<const float4*>(p + 4);
  union { unsigned int u[4]; short8 s; } cv;
  cv.u[0] = bfpack(v0.x, v0.y);
  cv.u[1] = bfpack(v0.z, v0.w);
  cv.u[2] = bfpack(v1.x, v1.y);
  cv.u[3] = bfpack(v1.z, v1.w);
  return cv.s;
}

// 512 threads = 8 waves. Block: 32 batch rows; wave w owns 32 rows x h in [w*64, w*64+64).
template <bool USE_WS>
__global__
__attribute__((amdgpu_flat_work_group_size(512, 512)))
void snn_main(const float* __restrict__ x,
              const unsigned short* __restrict__ w1bf,  // bf16 W1 (if USE_WS)
              const float* __restrict__ w1f,            // fp32 W1 (fallback)
              const float* __restrict__ b1,
              const float* __restrict__ w2,
              const float* __restrict__ b2,
              float* __restrict__ out)
{
  // mem1 planes 0..6 in LDS (per-thread f32x4 slots, 0-conflict); plane 7 (rt1,ct3) in regs
  __shared__ __align__(16) float mem_lds[7][512][4];       // 57,344 B
  __shared__ __align__(16) unsigned short xt[2][32][132];  // dbuf k-half staging, 16,896 B
  __shared__ float red[32][9];                             // 1,152 B  (total 75,392 B)

  const int tid  = threadIdx.x;
  const int lane = tid & 63;
  const int wave = tid >> 6;          // 0..7
  const int l15  = lane & 15;
  const int lq   = lane >> 4;         // 0..3
  const long b0  = (long)blockIdx.x * 32;
  const int h0   = wave * 64;         // 64 h-cols per wave (4 col-tiles of 16)

  float w2l[4], b1l[4];
#pragma unroll
  for (int ct = 0; ct < 4; ++ct) {
    int h = h0 + ct * 16 + l15;
    w2l[ct] = w2[h];
    b1l[ct] = b1[h];
  }
  const float bias2 = b2[0];

  // init mem1 planes (own slot, no barrier needed) + plane7 regs
#pragma unroll
  for (int p = 0; p < 7; ++p) {
    f32x4 z = {0.f, 0.f, 0.f, 0.f};
    *reinterpret_cast<f32x4*>(&mem_lds[p][tid][0]) = z;
  }
  f32x4 m7 = {0.f, 0.f, 0.f, 0.f};

  float mem2 = 0.f, spksum = 0.f;   // per-thread redundant (16 replicas per row)

  // staging geometry: thread -> row sr (0..31), float4 col sc (0..15); 2 float4 per half
  const int sr = tid >> 4;
  const int sc = tid & 15;
  const float* xrow = x + (b0 + sr) * 2560;   // + t*256 + half*128 + {sc*4, sc*4+64}

  // W1 fragment base (ct offset = ct*4096 shorts applied per use)
  const unsigned short* wb = w1bf + (h0 + l15) * 256 + lq * 8;
  const float*          wf = w1f  + (h0 + l15) * 256 + lq * 8;

  // prologue: load+cvt half0 of t=0  (pf = 4 VGPRs)
  uint2 pfa, pfb;
  {
    const float4 v0 = *reinterpret_cast<const float4*>(xrow + sc * 4);
    const float4 v1 = *reinterpret_cast<const float4*>(xrow + sc * 4 + 64);
    pfa = make_uint2(bfpack(v0.x, v0.y), bfpack(v0.z, v0.w));
    pfb = make_uint2(bfpack(v1.x, v1.y), bfpack(v1.z, v1.w));
  }

#pragma unroll 1
  for (int t = 0; t < 10; ++t) {
    // ---- A: write half0 -> xt[0]; load+cvt half1 of t ----
    *reinterpret_cast<uint2*>(&xt[0][sr][sc * 4]) = pfa;
    *reinterpret_cast<uint2*>(&xt[0][sr][sc * 4 + 64]) = pfb;
    {
      const float4 v0 = *reinterpret_cast<const float4*>(xrow + t * 256 + 128 + sc * 4);
      const float4 v1 = *reinterpret_cast<const float4*>(xrow + t * 256 + 128 + sc * 4 + 64);
      pfa = make_uint2(bfpack(v0.x, v0.y), bfpack(v0.z, v0.w));
      pfb = make_uint2(bfpack(v1.x, v1.y), bfpack(v1.z, v1.w));
    }
    __syncthreads();   // bar1: xt[0] ready

    // ======== PASS 0: cols ct=0,1 ========
    f32x4 acc0[2][2];
#pragma unroll
    for (int rt = 0; rt < 2; ++rt)
#pragma unroll
      for (int c = 0; c < 2; ++c) {
        f32x4 cc = { b1l[c], b1l[c], b1l[c], b1l[c] };
        acc0[rt][c] = cc;
      }

    // kk 0..3 from xt[0]
#pragma unroll
    for (int kk = 0; kk < 4; ++kk) {
      short8 a[2], bfr[2];
#pragma unroll
      for (int rt = 0; rt < 2; ++rt)
        a[rt] = *reinterpret_cast<const short8*>(&xt[0][rt * 16 + l15][kk * 32 + lq * 8]);
#pragma unroll
      for (int c = 0; c < 2; ++c) {
        if constexpr (USE_WS) bfr[c] = *reinterpret_cast<const short8*>(wb + c * 4096 + kk * 32);
        else                  bfr[c] = cvt_frag(wf + c * 4096 + kk * 32);
      }
#pragma unroll
      for (int rt = 0; rt < 2; ++rt)
#pragma unroll
        for (int c = 0; c < 2; ++c)
          acc0[rt][c] = __builtin_amdgcn_mfma_f32_16x16x32_bf16(a[rt], bfr[c], acc0[rt][c], 0, 0, 0);
    }

    // write half1 -> xt[1]; load half0 of t+1
    *reinterpret_cast<uint2*>(&xt[1][sr][sc * 4]) = pfa;
    *reinterpret_cast<uint2*>(&xt[1][sr][sc * 4 + 64]) = pfb;
    {
      const int tn = (t < 9) ? t + 1 : 9;   // tail: harmless re-read
      const float4 v0 = *reinterpret_cast<const float4*>(xrow + tn * 256 + sc * 4);
      const float4 v1 = *reinterpret_cast<const float4*>(xrow + tn * 256 + sc * 4 + 64);
      pfa = make_uint2(bfpack(v0.x, v0.y), bfpack(v0.z, v0.w));
      pfb = make_uint2(bfpack(v1.x, v1.y), bfpack(v1.z, v1.w));
    }
    __syncthreads();   // bar2: xt[1] ready

    // kk 4..7 from xt[1]
#pragma unroll
    for (int kkL = 0; kkL < 4; ++kkL) {
      const int kk = 4 + kkL;
      short8 a[2], bfr[2];
#pragma unroll
      for (int rt = 0; rt < 2; ++rt)
        a[rt] = *reinterpret_cast<const short8*>(&xt[1][rt * 16 + l15][kkL * 32 + lq * 8]);
#pragma unroll
      for (int c = 0; c < 2; ++c) {
        if constexpr (USE_WS) bfr[c] = *reinterpret_cast<const short8*>(wb + c * 4096 + kk * 32);
        else                  bfr[c] = cvt_frag(wf + c * 4096 + kk * 32);
      }
#pragma unroll
      for (int rt = 0; rt < 2; ++rt)
#pragma unroll
        for (int c = 0; c < 2; ++c)
          acc0[rt][c] = __builtin_amdgcn_mfma_f32_16x16x32_bf16(a[rt], bfr[c], acc0[rt][c], 0, 0, 0);
    }

    // LIF pass 0 (planes rt*4 + {0,1}) + red write (=)
#pragma unroll
    for (int rt = 0; rt < 2; ++rt) {
      float pr[4] = {0.f, 0.f, 0.f, 0.f};
#pragma unroll
      for (int c = 0; c < 2; ++c) {
        const int p = rt * 4 + c;   // 0,1,4,5 -> all LDS
        f32x4* slot = reinterpret_cast<f32x4*>(&mem_lds[p][tid][0]);
        f32x4 mv = *slot;
#pragma unroll
        for (int e = 0; e < 4; ++e) {
          float m   = fmaf(mv[e], 0.9f, acc0[rt][c][e]);
          float spk = fast_sigmoid(fmaf(m, 10.f, -10.f));
          mv[e] = m - spk;
          pr[e] = fmaf(spk, w2l[c], pr[e]);
        }
        *slot = mv;
      }
#pragma unroll
      for (int e = 0; e < 4; ++e) {
        float v = pr[e];
        v += __shfl_xor(v, 1);
        v += __shfl_xor(v, 2);
        v += __shfl_xor(v, 4);
        v += __shfl_xor(v, 8);
        if (l15 == 0) red[rt * 16 + lq * 4 + e][wave] = v;
      }
    }

    // ======== PASS 1: cols ct=2,3 ========
    f32x4 acc1[2][2];
#pragma unroll
    for (int rt = 0; rt < 2; ++rt)
#pragma unroll
      for (int c = 0; c < 2; ++c) {
        f32x4 cc = { b1l[2 + c], b1l[2 + c], b1l[2 + c], b1l[2 + c] };
        acc1[rt][c] = cc;
      }

#pragma unroll
    for (int kk = 0; kk < 4; ++kk) {   // kk 0..3 from xt[0] (still valid until bar3)
      short8 a[2], bfr[2];
#pragma unroll
      for (int rt = 0; rt < 2; ++rt)
        a[rt] = *reinterpret_cast<const short8*>(&xt[0][rt * 16 + l15][kk * 32 + lq * 8]);
#pragma unroll
      for (int c = 0; c < 2; ++c) {
        if constexpr (USE_WS) bfr[c] = *reinterpret_cast<const short8*>(wb + (2 + c) * 4096 + kk * 32);
        else                  bfr[c] = cvt_frag(wf + (2 + c) * 4096 + kk * 32);
      }
#pragma unroll
      for (int rt = 0; rt < 2; ++rt)
#pragma unroll
        for (int c = 0; c < 2; ++c)
          acc1[rt][c] = __builtin_amdgcn_mfma_f32_16x16x32_bf16(a[rt], bfr[c], acc1[rt][c], 0, 0, 0);
    }
#pragma unroll
    for (int kkL = 0; kkL < 4; ++kkL) {  // kk 4..7 from xt[1]
      const int kk = 4 + kkL;
      short8 a[2], bfr[2];
#pragma unroll
      for (int rt = 0; rt < 2; ++rt)
        a[rt] = *reinterpret_cast<const short8*>(&xt[1][rt * 16 + l15][kkL * 32 + lq * 8]);
#pragma unroll
      for (int c = 0; c < 2; ++c) {
        if constexpr (USE_WS) bfr[c] = *reinterpret_cast<const short8*>(wb + (2 + c) * 4096 + kk * 32);
        else                  bfr[c] = cvt_frag(wf + (2 + c) * 4096 + kk * 32);
      }
#pragma unroll
      for (int rt = 0; rt < 2; ++rt)
#pragma unroll
        for (int c = 0; c < 2; ++c)
          acc1[rt][c] = __builtin_amdgcn_mfma_f32_16x16x32_bf16(a[rt], bfr[c], acc1[rt][c], 0, 0, 0);
    }

    // LIF pass 1 (planes rt*4 + {2,3}; plane 7 in regs) + red accumulate (+=)
#pragma unroll
    for (int rt = 0; rt < 2; ++rt) {
      float pr[4] = {0.f, 0.f, 0.f, 0.f};
#pragma unroll
      for (int c = 0; c < 2; ++c) {
        const int p = rt * 4 + 2 + c;   // 2,3,6,7
        f32x4 mv;
        if (p < 7) mv = *reinterpret_cast<f32x4*>(&mem_lds[p][tid][0]);
        else       mv = m7;
#pragma unroll
        for (int e = 0; e < 4; ++e) {
          float m   = fmaf(mv[e], 0.9f, acc1[rt][c][e]);
          float spk = fast_sigmoid(fmaf(m, 10.f, -10.f));
          mv[e] = m - spk;
          pr[e] = fmaf(spk, w2l[2 + c], pr[e]);
        }
        if (p < 7) *reinterpret_cast<f32x4*>(&mem_lds[p][tid][0]) = mv;
        else       m7 = mv;
      }
#pragma unroll
      for (int e = 0; e < 4; ++e) {
        float v = pr[e];
        v += __shfl_xor(v, 1);
        v += __shfl_xor(v, 2);
        v += __shfl_xor(v, 4);
        v += __shfl_xor(v, 8);
        if (l15 == 0) red[rt * 16 + lq * 4 + e][wave] += v;
      }
    }
    __syncthreads();   // bar3: red complete

    // ---- LIF2, redundant on all threads (row = lane&31). Next red write is in
    //      pass0-LIF of t+1, behind bar1(t+1) and bar2(t+1) -> safe. ----
    {
      float c2 = bias2;
#pragma unroll
      for (int w = 0; w < 8; ++w) c2 += red[lane & 31][w];
      float m   = fmaf(mem2, 0.9f, c2);
      float spk = fast_sigmoid(fmaf(m, 10.f, -10.f));
      mem2   = m - spk;
      spksum += spk;
    }
  }

  if (tid < 32) {
    float y = fast_sigmoid(spksum * 0.1f);
    out[b0 + tid] = y;                      // FLOAT32 output
  }
}

extern "C" void kernel_launch(void* const* d_in, const int* in_sizes, int n_in,
                              void* d_out, int out_size, void* d_ws, size_t ws_size,
                              hipStream_t stream) {
  const float* x  = (const float*)d_in[0];
  const float* W1 = (const float*)d_in[1];
  const float* b1 = (const float*)d_in[2];
  const float* W2 = (const float*)d_in[3];
  const float* b2 = (const float*)d_in[4];
  float* out = (float*)d_out;
  (void)in_sizes; (void)n_in;

  const int grid = out_size / 32;   // out_size == B == 32768 -> 1024 blocks

  if (ws_size >= 512 * 256 * sizeof(unsigned short)) {
    unsigned short* w1bf = (unsigned short*)d_ws;   // 256 KB
    w1_to_bf16<<<128, 256, 0, stream>>>(W1, w1bf);
    snn_main<true><<<grid, 512, 0, stream>>>(x, w1bf, W1, b1, W2, b2, out);
  } else {
    snn_main<false><<<grid, 512, 0, stream>>>(x, nullptr, W1, b1, W2, b2, out);
  }
}

// Round 14
// 221.856 us; speedup vs baseline: 1.0824x; 1.0824x over previous
//
#include <hip/hip_runtime.h>
#include <hip/hip_bf16.h>

// FraudSNN fused kernel: GEMM (bf16 MFMA) + LIF recurrence, T=10, F=256, H=512.
// R14: 2 barriers/t with a SINGLE full-t xt buffer (writes A(t+1) vs reads B(t) are
// separated by bar2; reads B(t+1) behind bar1). One global x load point per t, issued
// a full t-phase ahead (~4-8K cyc cover vs R13's ~500) -> pf stall removed.
// Keeps R13 ct-pair split (acc 16 regs, LIF per pass), planes m5/m6/m7 in regs,
// 5 mem1 planes in LDS. LDS 59 KB; live ~80 regs < the 128 budget proven at 512 thr.

typedef short short8 __attribute__((ext_vector_type(8)));
typedef float f32x4 __attribute__((ext_vector_type(4)));

__device__ __forceinline__ unsigned short bfbits(float f) {
  union { __hip_bfloat16 h; unsigned short u; } c;
  c.h = __float2bfloat16(f);   // hardware RNE
  return c.u;
}

__device__ __forceinline__ unsigned int bfpack(float a, float b) {
  return (unsigned int)bfbits(a) | ((unsigned int)bfbits(b) << 16);
}

__device__ __forceinline__ float fast_sigmoid(float z) {
  float e = __expf(-z);
  return __builtin_amdgcn_rcpf(1.0f + e);
}

__device__ __forceinline__ void lif4(f32x4& mv, const f32x4 av, float w2c, float pr[4]) {
#pragma unroll
  for (int e = 0; e < 4; ++e) {
    float m   = fmaf(mv[e], 0.9f, av[e]);     // beta*mem + cur1
    float spk = fast_sigmoid(fmaf(m, 10.f, -10.f));
    mv[e] = m - spk;
    pr[e] = fmaf(spk, w2c, pr[e]);
  }
}

__global__ void w1_to_bf16(const float* __restrict__ w1, unsigned short* __restrict__ o) {
  int i = blockIdx.x * 256 + threadIdx.x;      // 32768 float4s
  float4 v = reinterpret_cast<const float4*>(w1)[i];
  reinterpret_cast<uint2*>(o)[i] = make_uint2(bfpack(v.x, v.y), bfpack(v.z, v.w));
}

__device__ __forceinline__ short8 cvt_frag(const float* p) {
  const float4 v0 = *reinterpret_cast<const float4*>(p);
  const float4 v1 = *reinterpret_cast<const float4*>(p + 4);
  union { unsigned int u[4]; short8 s; } cv;
  cv.u[0] = bfpack(v0.x, v0.y);
  cv.u[1] = bfpack(v0.z, v0.w);
  cv.u[2] = bfpack(v1.x, v1.y);
  cv.u[3] = bfpack(v1.z, v1.w);
  return cv.s;
}

// 512 threads = 8 waves. Block: 32 batch rows; wave w owns 32 rows x h in [w*64, w*64+64).
template <bool USE_WS>
__global__
__attribute__((amdgpu_flat_work_group_size(512, 512)))
void snn_main(const float* __restrict__ x,
              const unsigned short* __restrict__ w1bf,  // bf16 W1 (if USE_WS)
              const float* __restrict__ w1f,            // fp32 W1 (fallback)
              const float* __restrict__ b1,
              const float* __restrict__ w2,
              const float* __restrict__ b2,
              float* __restrict__ out)
{
  // mem1 planes 0..4 in LDS (per-thread f32x4 slots, 0-conflict); planes 5,6,7 in regs
  __shared__ __align__(16) float mem_lds[5][512][4];    // 40,960 B
  __shared__ __align__(16) unsigned short xt[32][264];  // full-t staging, 16,896 B
  __shared__ float red[32][9];                          // 1,152 B   (total 59,008 B)

  const int tid  = threadIdx.x;
  const int lane = tid & 63;
  const int wave = tid >> 6;          // 0..7
  const int l15  = lane & 15;
  const int lq   = lane >> 4;         // 0..3
  const long b0  = (long)blockIdx.x * 32;
  const int h0   = wave * 64;         // 4 col-tiles of 16

  float w2l[4], b1l[4];
#pragma unroll
  for (int ct = 0; ct < 4; ++ct) {
    int h = h0 + ct * 16 + l15;
    w2l[ct] = w2[h];
    b1l[ct] = b1[h];
  }
  const float bias2 = b2[0];

  // init mem1: LDS planes 0..4 (own slot; first barrier fences), reg planes 5..7
#pragma unroll
  for (int p = 0; p < 5; ++p) {
    f32x4 z = {0.f, 0.f, 0.f, 0.f};
    *reinterpret_cast<f32x4*>(&mem_lds[p][tid][0]) = z;
  }
  f32x4 m5 = {0.f, 0.f, 0.f, 0.f}, m6 = m5, m7 = m5;

  float mem2 = 0.f, spksum = 0.f;   // per-thread redundant (16 replicas per row)

  // staging: thread -> row sr (0..31), float4 col sc (0..15); 4 float4 per t (full row)
  const int sr = tid >> 4;
  const int sc = tid & 15;
  const float* xrow = x + (b0 + sr) * 2560;

  // W1 fragment base (ct offset = ct*4096 shorts / floats per use)
  const unsigned short* wb = w1bf + (h0 + l15) * 256 + lq * 8;
  const float*          wf = w1f  + (h0 + l15) * 256 + lq * 8;

  // prologue: load+pack full row of t=0 (pf = 4 uint2 = 8 VGPR)
  uint2 pf[4];
#pragma unroll
  for (int j = 0; j < 4; ++j) {
    const float4 v = *reinterpret_cast<const float4*>(xrow + sc * 4 + j * 64);
    pf[j] = make_uint2(bfpack(v.x, v.y), bfpack(v.z, v.w));
  }

#pragma unroll 1
  for (int t = 0; t < 10; ++t) {
    // ---- A: write pf(t) -> xt; issue+pack loads for t+1 (cover = full t-phase) ----
#pragma unroll
    for (int j = 0; j < 4; ++j)
      *reinterpret_cast<uint2*>(&xt[sr][sc * 4 + j * 64]) = pf[j];
    {
      const int tn = (t < 9) ? t + 1 : 9;   // tail: harmless re-read
#pragma unroll
      for (int j = 0; j < 4; ++j) {
        const float4 v = *reinterpret_cast<const float4*>(xrow + tn * 256 + sc * 4 + j * 64);
        pf[j] = make_uint2(bfpack(v.x, v.y), bfpack(v.z, v.w));
      }
    }
    __syncthreads();   // bar1: xt ready

    // ======== PASS 0: col-tiles 0,1 ========
    f32x4 acc[2][2];
#pragma unroll
    for (int rt = 0; rt < 2; ++rt)
#pragma unroll
      for (int c = 0; c < 2; ++c) {
        f32x4 cc = { b1l[c], b1l[c], b1l[c], b1l[c] };
        acc[rt][c] = cc;
      }
#pragma unroll
    for (int kk = 0; kk < 8; ++kk) {
      short8 a[2], bfr[2];
#pragma unroll
      for (int rt = 0; rt < 2; ++rt)
        a[rt] = *reinterpret_cast<const short8*>(&xt[rt * 16 + l15][kk * 32 + lq * 8]);
#pragma unroll
      for (int c = 0; c < 2; ++c) {
        if constexpr (USE_WS) bfr[c] = *reinterpret_cast<const short8*>(wb + c * 4096 + kk * 32);
        else                  bfr[c] = cvt_frag(wf + c * 4096 + kk * 32);
      }
#pragma unroll
      for (int rt = 0; rt < 2; ++rt)
#pragma unroll
        for (int c = 0; c < 2; ++c)
          acc[rt][c] = __builtin_amdgcn_mfma_f32_16x16x32_bf16(a[rt], bfr[c], acc[rt][c], 0, 0, 0);
    }
    // LIF pass0: planes (rt0:c0,c1)->lds0,lds1 ; (rt1:c0)->lds4 ; (rt1:c1)->m5 ; red =
    {
      float pr[4] = {0.f, 0.f, 0.f, 0.f};
      f32x4 mv;
      mv = *reinterpret_cast<f32x4*>(&mem_lds[0][tid][0]);
      lif4(mv, acc[0][0], w2l[0], pr);
      *reinterpret_cast<f32x4*>(&mem_lds[0][tid][0]) = mv;
      mv = *reinterpret_cast<f32x4*>(&mem_lds[1][tid][0]);
      lif4(mv, acc[0][1], w2l[1], pr);
      *reinterpret_cast<f32x4*>(&mem_lds[1][tid][0]) = mv;
#pragma unroll
      for (int e = 0; e < 4; ++e) {
        float v = pr[e];
        v += __shfl_xor(v, 1); v += __shfl_xor(v, 2);
        v += __shfl_xor(v, 4); v += __shfl_xor(v, 8);
        if (l15 == 0) red[lq * 4 + e][wave] = v;
      }
      float pr1[4] = {0.f, 0.f, 0.f, 0.f};
      mv = *reinterpret_cast<f32x4*>(&mem_lds[4][tid][0]);
      lif4(mv, acc[1][0], w2l[0], pr1);
      *reinterpret_cast<f32x4*>(&mem_lds[4][tid][0]) = mv;
      lif4(m5, acc[1][1], w2l[1], pr1);
#pragma unroll
      for (int e = 0; e < 4; ++e) {
        float v = pr1[e];
        v += __shfl_xor(v, 1); v += __shfl_xor(v, 2);
        v += __shfl_xor(v, 4); v += __shfl_xor(v, 8);
        if (l15 == 0) red[16 + lq * 4 + e][wave] = v;
      }
    }

    // ======== PASS 1: col-tiles 2,3 ========
#pragma unroll
    for (int rt = 0; rt < 2; ++rt)
#pragma unroll
      for (int c = 0; c < 2; ++c) {
        f32x4 cc = { b1l[2 + c], b1l[2 + c], b1l[2 + c], b1l[2 + c] };
        acc[rt][c] = cc;
      }
#pragma unroll
    for (int kk = 0; kk < 8; ++kk) {
      short8 a[2], bfr[2];
#pragma unroll
      for (int rt = 0; rt < 2; ++rt)
        a[rt] = *reinterpret_cast<const short8*>(&xt[rt * 16 + l15][kk * 32 + lq * 8]);
#pragma unroll
      for (int c = 0; c < 2; ++c) {
        if constexpr (USE_WS) bfr[c] = *reinterpret_cast<const short8*>(wb + (2 + c) * 4096 + kk * 32);
        else                  bfr[c] = cvt_frag(wf + (2 + c) * 4096 + kk * 32);
      }
#pragma unroll
      for (int rt = 0; rt < 2; ++rt)
#pragma unroll
        for (int c = 0; c < 2; ++c)
          acc[rt][c] = __builtin_amdgcn_mfma_f32_16x16x32_bf16(a[rt], bfr[c], acc[rt][c], 0, 0, 0);
    }
    // LIF pass1: (rt0:c2)->lds2 ; (rt0:c3)->lds3 ; (rt1:c2)->m6 ; (rt1:c3)->m7 ; red +=
    {
      float pr[4] = {0.f, 0.f, 0.f, 0.f};
      f32x4 mv;
      mv = *reinterpret_cast<f32x4*>(&mem_lds[2][tid][0]);
      lif4(mv, acc[0][0], w2l[2], pr);
      *reinterpret_cast<f32x4*>(&mem_lds[2][tid][0]) = mv;
      mv = *reinterpret_cast<f32x4*>(&mem_lds[3][tid][0]);
      lif4(mv, acc[0][1], w2l[3], pr);
      *reinterpret_cast<f32x4*>(&mem_lds[3][tid][0]) = mv;
#pragma unroll
      for (int e = 0; e < 4; ++e) {
        float v = pr[e];
        v += __shfl_xor(v, 1); v += __shfl_xor(v, 2);
        v += __shfl_xor(v, 4); v += __shfl_xor(v, 8);
        if (l15 == 0) red[lq * 4 + e][wave] += v;
      }
      float pr1[4] = {0.f, 0.f, 0.f, 0.f};
      lif4(m6, acc[1][0], w2l[2], pr1);
      lif4(m7, acc[1][1], w2l[3], pr1);
#pragma unroll
      for (int e = 0; e < 4; ++e) {
        float v = pr1[e];
        v += __shfl_xor(v, 1); v += __shfl_xor(v, 2);
        v += __shfl_xor(v, 4); v += __shfl_xor(v, 8);
        if (l15 == 0) red[16 + lq * 4 + e][wave] += v;
      }
    }
    __syncthreads();   // bar2: red complete; xt reads done (A(t+1) may overwrite)

    // ---- LIF2, redundant on all threads (row = lane&31) ----
    {
      float c2 = bias2;
#pragma unroll
      for (int w = 0; w < 8; ++w) c2 += red[lane & 31][w];
      float m   = fmaf(mem2, 0.9f, c2);
      float spk = fast_sigmoid(fmaf(m, 10.f, -10.f));
      mem2   = m - spk;
      spksum += spk;
    }
  }

  if (tid < 32) {
    float y = fast_sigmoid(spksum * 0.1f);
    out[b0 + tid] = y;                      // FLOAT32 output
  }
}

extern "C" void kernel_launch(void* const* d_in, const int* in_sizes, int n_in,
                              void* d_out, int out_size, void* d_ws, size_t ws_size,
                              hipStream_t stream) {
  const float* x  = (const float*)d_in[0];
  const float* W1 = (const float*)d_in[1];
  const float* b1 = (const float*)d_in[2];
  const float* W2 = (const float*)d_in[3];
  const float* b2 = (const float*)d_in[4];
  float* out = (float*)d_out;
  (void)in_sizes; (void)n_in;

  const int grid = out_size / 32;   // out_size == B == 32768 -> 1024 blocks

  if (ws_size >= 512 * 256 * sizeof(unsigned short)) {
    unsigned short* w1bf = (unsigned short*)d_ws;   // 256 KB
    w1_to_bf16<<<128, 256, 0, stream>>>(W1, w1bf);
    snn_main<true><<<grid, 512, 0, stream>>>(x, w1bf, W1, b1, W2, b2, out);
  } else {
    snn_main<false><<<grid, 512, 0, stream>>>(x, nullptr, W1, b1, W2, b2, out);
  }
}